// Round 11
// baseline (4601.012 us; speedup 1.0000x reference)
//
#include <hip/hip_runtime.h>
#include <math.h>

namespace {
constexpr int T_ = 32, B_ = 32, H_ = 512, S_ = 512;
constexpr int BH = B_ * H_;     // 16384
constexpr int LSTM_NWG = 256;
// ws float offsets
constexpr size_t O_EMBS = 0;                          // [T*B][H]
constexpr size_t O_H0   = O_EMBS + (size_t)T_ * BH;   // [2][BH]
constexpr size_t O_H1   = O_H0 + 2 * BH;              // [2][BH]
constexpr size_t O_GC   = O_H1 + 2 * BH;              // gamma [1024][512]
constexpr size_t O_CTC  = O_GC + (size_t)1024 * 512;  // ct
constexpr size_t O_OCV  = O_CTC + (size_t)1024 * 512; // out_conv
}

// Monotonic barrier state (zero-init at load, survives graph replays, immune
// to 0xAA ws poison). Used only by k_lstm.
__device__ unsigned g_arrive[LSTM_NWG] = {};
__device__ unsigned g_go = 0;

static __device__ __forceinline__ float sigm(float x) { return 1.0f / (1.0f + expf(-x)); }
static __device__ __forceinline__ float dot4(float4 a, float4 b) {
  return a.x * b.x + a.y * b.y + a.z * b.z + a.w * b.w;
}
static __device__ __forceinline__ void fma4(float4& a, float s, float4 x) {
  a.x += s * x.x; a.y += s * x.y; a.z += s * x.z; a.w += s * x.w;
}
static __device__ __forceinline__ void scale_fma4(float4& a, float f, float e, float4 x) {
  a.x = a.x * f + e * x.x; a.y = a.y * f + e * x.y;
  a.z = a.z * f + e * x.z; a.w = a.w * f + e * x.w;
}

// Fence-free grid barrier (validated round 7). Cross-WG data moves via sc1
// accesses that bypass L2; barrier needs only vmcnt drain + flag atomics.
static __device__ __forceinline__ void grid_barrier_light(unsigned target) {
  asm volatile("s_waitcnt vmcnt(0)" ::: "memory");  // drain own sc1 h-stores
  __syncthreads();
  if (threadIdx.x == 0)
    __hip_atomic_store(&g_arrive[blockIdx.x], target, __ATOMIC_RELAXED,
                       __HIP_MEMORY_SCOPE_AGENT);
  if (blockIdx.x == 0) {
    for (int i = threadIdx.x; i < LSTM_NWG; i += 512)
      while (__hip_atomic_load(&g_arrive[i], __ATOMIC_RELAXED,
                               __HIP_MEMORY_SCOPE_AGENT) < target)
        __builtin_amdgcn_s_sleep(1);
    __syncthreads();
    if (threadIdx.x == 0)
      __hip_atomic_store(&g_go, target, __ATOMIC_RELAXED,
                         __HIP_MEMORY_SCOPE_AGENT);
  }
  if (threadIdx.x == 0)
    while (__hip_atomic_load(&g_go, __ATOMIC_RELAXED,
                             __HIP_MEMORY_SCOPE_AGENT) < target)
      __builtin_amdgcn_s_sleep(1);
  __syncthreads();
  asm volatile("" ::: "memory");   // compiler barrier: no load hoisting
}

// ---------------- K1: init state + embedding gather ----------------
__global__ __launch_bounds__(512)
void k_init(const int* __restrict__ inputs, const float* __restrict__ h0in,
            const float* __restrict__ emb, float* __restrict__ ws) {
  const int g = blockIdx.x, tid = threadIdx.x;
  const int gid = g * 512 + tid;
  // Ping parity: layer-0 initial h in ping 0; layer-1 initial h in ping 1.
  if (gid < BH) {
    ws[O_H0 + gid]      = h0in[gid];
    ws[O_H1 + BH + gid] = h0in[BH + gid];
  }
#pragma unroll
  for (int r = 0; r < 4; ++r) {
    const int tb = g * 4 + r;
    ws[O_EMBS + (size_t)tb * H_ + tid] = emb[(size_t)inputs[tb] * H_ + tid];
  }
}

// ---------------- K2: persistent LSTM chain, register-resident weights -----
// 256 WGs x 512 threads, 1 WG/CU. WG = (cell = g>>7, quad q = g&127) owning
// cols j = q*4..+3. Thread = (jj = tid&3 col, gp = (tid>>2)&1 gate-pair,
// ks = (tid>>3)&31 K-window of 16(x)+16(h), b8 = tid>>8 b-half of 16).
// Weights per thread: 2 gates x (16 x + 16 h) = 64 floats = 64 VGPRs (named
// float4[4] arrays, static indices only). acc 2x16 = 32 VGPRs. Round-9/10
// lesson: the 4-gate/8-b variant needed ~220 VGPRs; compiler capped at 128
// and spilled weights to scratch (10 GB/dispatch HBM traffic). This mapping
// fits the budget; amdgpu_waves_per_eu(2,2) additionally requests the
// 256-VGPR budget (2 waves/EU).
__global__ __attribute__((amdgpu_waves_per_eu(2, 2))) __launch_bounds__(512)
void k_lstm(const float* __restrict__ W_ih, const float* __restrict__ W_hh,
            const float* __restrict__ b_ih, const float* __restrict__ b_hh,
            const float* __restrict__ c0in, float* __restrict__ out,
            float* __restrict__ ws) {
  const int g = blockIdx.x, tid = threadIdx.x;
  const int cell = g >> 7, q = g & 127;
  const int jj = tid & 3, gp = (tid >> 2) & 1, ks = (tid >> 3) & 31, b8 = tid >> 8;
  float* EMBS = ws + O_EMBS;
  float* H0 = ws + O_H0;
  float* H1 = ws + O_H1;

  __shared__ __align__(16) float stgA[16512];   // operand A / red / w-bounce
  __shared__ __align__(16) float stgB[16512];   // operand B
  __shared__ float gates[512];

  // ---- one-time: weights into registers via coalesced LDS bounce ----
  // Per pass: 16 rows (row = col*4 + gate) x 512 floats = 2048 float4 -> i<4.
  float4 w0a[4], w0b[4], w1a[4], w1b[4];   // [x|h] x [gate gp*2 | gp*2+1]
  {
    const float* Wih = W_ih + (size_t)cell * 4 * H_ * H_;
    const float* Whh = W_hh + (size_t)cell * 4 * H_ * H_;
#pragma unroll
    for (int pass = 0; pass < 2; ++pass) {
      const float* Wsrc = pass ? Whh : Wih;
#pragma unroll
      for (int i = 0; i < 4; ++i) {
        const int d4 = tid + i * 512;          // float4 idx 0..2047
        const int lrow = d4 >> 7;              // 0..15
        const int f4 = d4 & 127;               // 0..127
        const int rr = lrow & 3, jx = lrow >> 2;   // gate, col (0..3)
        const float4 v = *(const float4*)&Wsrc[((size_t)rr * H_ + q * 4 + jx) * H_ + f4 * 4];
        *(float4*)&stgA[lrow * 1028 + f4 * 4] = v;
      }
      __syncthreads();
      {
        const int rowA = jj * 4 + gp * 2;      // gate gp*2 of col jj
        const int rowB = rowA + 1;             // gate gp*2+1
#pragma unroll
        for (int f = 0; f < 4; ++f) {
          const float4 va = *(const float4*)&stgA[rowA * 1028 + ks * 16 + f * 4];
          const float4 vb = *(const float4*)&stgA[rowB * 1028 + ks * 16 + f * 4];
          if (pass) { w1a[f] = va; w1b[f] = vb; }
          else      { w0a[f] = va; w0b[f] = vb; }
        }
      }
      __syncthreads();
    }
  }
  // ---- one-time: bias sums + c-state for finalize threads (tid < 128) ----
  float creg = 0.f, bs0 = 0.f, bs1 = 0.f, bs2 = 0.f, bs3 = 0.f;
  if (tid < 128) {
    const int fj = tid >> 5, fb = tid & 31;
    const int fjo = q * 4 + fj;
    creg = c0in[cell * BH + fb * H_ + fjo];
    const float* bi = b_ih + (size_t)cell * 4 * H_;
    const float* bh = b_hh + (size_t)cell * 4 * H_;
    bs0 = bi[0 * H_ + fjo] + bh[0 * H_ + fjo];
    bs1 = bi[1 * H_ + fjo] + bh[1 * H_ + fjo];
    bs2 = bi[2 * H_ + fjo] + bh[2 * H_ + fjo];
    bs3 = bi[3 * H_ + fjo] + bh[3 * H_ + fjo];
  }

  unsigned bar = __hip_atomic_load(&g_go, __ATOMIC_RELAXED,
                                   __HIP_MEMORY_SCOPE_AGENT);

  for (int s = 0; s <= T_; ++s) {
    const int pi = s & 1, qi = pi ^ 1;
    const bool act = cell ? (s >= 1) : (s < T_);   // WG-uniform
    if (act) {
      // ---- stage both operands: A = x (512 K), B = h (512 K) ----
      if (cell == 0) {   // x = EMBS[s] (normal cached loads, L2-hot)
        const float* src = EMBS + (size_t)s * BH;
#pragma unroll
        for (int i = 0; i < 8; ++i) {
          const int d = tid + i * 512;
          const int b = d >> 7, k4 = d & 127;
          const float4 v = *(const float4*)(src + b * 512 + k4 * 4);
          *(float4*)&stgA[(k4 >> 2) * 516 + b * 16 + (k4 & 3) * 4] = v;
        }
      } else {           // x = H0[pi] (sc1 coherent)
        const float* src = H0 + pi * BH;
#pragma unroll
        for (int i = 0; i < 8; ++i) {
          const int d = tid + i * 512;
          const int b = d >> 7, k4 = d & 127;
          const float* p = src + b * 512 + k4 * 4;
          const unsigned long long u0 = __hip_atomic_load(
              (const unsigned long long*)p, __ATOMIC_RELAXED, __HIP_MEMORY_SCOPE_AGENT);
          const unsigned long long u1 = __hip_atomic_load(
              (const unsigned long long*)(p + 2), __ATOMIC_RELAXED, __HIP_MEMORY_SCOPE_AGENT);
          float4 v;
          v.x = __uint_as_float((unsigned)u0); v.y = __uint_as_float((unsigned)(u0 >> 32));
          v.z = __uint_as_float((unsigned)u1); v.w = __uint_as_float((unsigned)(u1 >> 32));
          *(float4*)&stgA[(k4 >> 2) * 516 + b * 16 + (k4 & 3) * 4] = v;
        }
      }
      {                  // h operand: cell0 -> H0[pi], cell1 -> H1[pi] (sc1)
        const float* src = (cell ? H1 : H0) + pi * BH;
#pragma unroll
        for (int i = 0; i < 8; ++i) {
          const int d = tid + i * 512;
          const int b = d >> 7, k4 = d & 127;
          const float* p = src + b * 512 + k4 * 4;
          const unsigned long long u0 = __hip_atomic_load(
              (const unsigned long long*)p, __ATOMIC_RELAXED, __HIP_MEMORY_SCOPE_AGENT);
          const unsigned long long u1 = __hip_atomic_load(
              (const unsigned long long*)(p + 2), __ATOMIC_RELAXED, __HIP_MEMORY_SCOPE_AGENT);
          float4 v;
          v.x = __uint_as_float((unsigned)u0); v.y = __uint_as_float((unsigned)(u0 >> 32));
          v.z = __uint_as_float((unsigned)u1); v.w = __uint_as_float((unsigned)(u1 >> 32));
          *(float4*)&stgB[(k4 >> 2) * 516 + b * 16 + (k4 & 3) * 4] = v;
        }
      }
      __syncthreads();

      // ---- MAC: 2 gates x 16 b over this thread's 16(x)+16(h) K window ----
      float acc_a[16], acc_b[16];
#pragma unroll
      for (int bi = 0; bi < 16; ++bi) { acc_a[bi] = 0.f; acc_b[bi] = 0.f; }
#pragma unroll
      for (int bi = 0; bi < 16; ++bi) {
        const float* hp = &stgA[ks * 516 + (b8 * 16 + bi) * 16];
        const float4 h0 = *(const float4*)(hp);
        const float4 h1 = *(const float4*)(hp + 4);
        const float4 h2 = *(const float4*)(hp + 8);
        const float4 h3 = *(const float4*)(hp + 12);
        acc_a[bi] += dot4(h0, w0a[0]) + dot4(h1, w0a[1])
                   + dot4(h2, w0a[2]) + dot4(h3, w0a[3]);
        acc_b[bi] += dot4(h0, w0b[0]) + dot4(h1, w0b[1])
                   + dot4(h2, w0b[2]) + dot4(h3, w0b[3]);
      }
#pragma unroll
      for (int bi = 0; bi < 16; ++bi) {
        const float* hp = &stgB[ks * 516 + (b8 * 16 + bi) * 16];
        const float4 h0 = *(const float4*)(hp);
        const float4 h1 = *(const float4*)(hp + 4);
        const float4 h2 = *(const float4*)(hp + 8);
        const float4 h3 = *(const float4*)(hp + 12);
        acc_a[bi] += dot4(h0, w1a[0]) + dot4(h1, w1a[1])
                   + dot4(h2, w1a[2]) + dot4(h3, w1a[3]);
        acc_b[bi] += dot4(h0, w1b[0]) + dot4(h1, w1b[1])
                   + dot4(h2, w1b[2]) + dot4(h3, w1b[3]);
      }
      __syncthreads();   // stgA/stgB consumed; stgA becomes red

      // ---- K-reduction: red[ks][row:16][b:32], stride 516 ----
      float* red = stgA;
      {
        const int rowA = jj * 4 + gp * 2;
        const int rowB = rowA + 1;
#pragma unroll
        for (int c = 0; c < 4; ++c) {
          *(float4*)&red[ks * 516 + rowA * 32 + b8 * 16 + c * 4] =
              make_float4(acc_a[c * 4], acc_a[c * 4 + 1],
                          acc_a[c * 4 + 2], acc_a[c * 4 + 3]);
          *(float4*)&red[ks * 516 + rowB * 32 + b8 * 16 + c * 4] =
              make_float4(acc_b[c * 4], acc_b[c * 4 + 1],
                          acc_b[c * 4 + 2], acc_b[c * 4 + 3]);
        }
      }
      __syncthreads();
      {
        const int row = tid >> 5, bb = tid & 31;
        float sum = 0.f;
#pragma unroll
        for (int k2 = 0; k2 < 32; ++k2) sum += red[k2 * 516 + row * 32 + bb];
        gates[row * 32 + bb] = sum;
      }
      __syncthreads();

      // ---- finalize: 128 threads = (fj in 4 cols, fb in 32 b) ----
      if (tid < 128) {
        const int fj = tid >> 5, fb = tid & 31;
        const int fjo = q * 4 + fj;
        const float gi  = gates[(fj * 4 + 0) * 32 + fb] + bs0;
        const float gf  = gates[(fj * 4 + 1) * 32 + fb] + bs1;
        const float gg  = gates[(fj * 4 + 2) * 32 + fb] + bs2;
        const float go_ = gates[(fj * 4 + 3) * 32 + fb] + bs3;
        const float cn = sigm(gf) * creg + sigm(gi) * tanhf(gg);
        const float hn = sigm(go_) * tanhf(cn);
        creg = cn;
        float* Hs = cell ? H1 : H0;
        __hip_atomic_store(&Hs[qi * BH + fb * H_ + fjo], hn,
                           __ATOMIC_RELAXED, __HIP_MEMORY_SCOPE_AGENT);
        if (cell)  // stash h1(t) rows (XH) in out[t]
          out[((size_t)(s - 1) * B_ + fb) * H_ + fjo] = hn;
        if (!cell && s == T_ - 1) {   // final h0/c0
          out[(size_t)T_ * BH + fb * H_ + fjo]          = hn;
          out[(size_t)T_ * BH + 2 * BH + fb * H_ + fjo] = cn;
        }
        if (cell && s == T_) {        // final h1/c1
          out[(size_t)T_ * BH + BH + fb * H_ + fjo]     = hn;
          out[(size_t)T_ * BH + 3 * BH + fb * H_ + fjo] = cn;
        }
      }
    }
    if (s < T_) grid_barrier_light(++bar);
  }
}

// ---------------- tiled GEMM: C[m][n] = ep(A[m][:] . W[n][:] + bias[n]) ----
template<bool TANH, bool RES>
__global__ __launch_bounds__(256)
void k_gemm(const float* __restrict__ A1, const float* __restrict__ A2,
            const float* __restrict__ W, const float* __restrict__ bias,
            const float* __restrict__ res, float* __restrict__ C, int dualA) {
  const int bid = blockIdx.x, tid = threadIdx.x;
  const int m0 = (bid & 31) * 32, n0 = (bid >> 5) * 32;
  const int tx = tid & 15, ty = tid >> 4;
  const int lr = tid >> 5, lc = tid & 31;
  const int nsteps = dualA ? 32 : 16;
  const int Krow = dualA ? 1024 : 512;
  __shared__ __align__(16) float Asm[32 * 33];
  __shared__ __align__(16) float Bsm[32 * 34];
  float acc00 = 0.f, acc01 = 0.f, acc10 = 0.f, acc11 = 0.f;

  for (int kt = 0; kt < nsteps; ++kt) {
    const float* A = (kt < 16) ? A1 : A2;
    const int ka = (kt < 16) ? kt * 32 : (kt - 16) * 32;
    const int kb = kt * 32;
    __syncthreads();
#pragma unroll
    for (int i = 0; i < 4; ++i) {
      const int row = lr + i * 8;
      Asm[row * 33 + lc] = A[(size_t)(m0 + row) * 512 + ka + lc];
      Bsm[lc * 34 + row] = W[(size_t)(n0 + row) * Krow + kb + lc];
    }
    __syncthreads();
#pragma unroll 8
    for (int k = 0; k < 32; ++k) {
      const float a0 = Asm[(ty * 2) * 33 + k];
      const float a1 = Asm[(ty * 2 + 1) * 33 + k];
      const float2 bv = *(const float2*)&Bsm[k * 34 + tx * 2];
      acc00 += a0 * bv.x; acc01 += a0 * bv.y;
      acc10 += a1 * bv.x; acc11 += a1 * bv.y;
    }
  }
  const int n = n0 + tx * 2;
  const int m = m0 + ty * 2;
  const float bx = bias[n], by = bias[n + 1];
  float v00 = acc00 + bx, v01 = acc01 + by;
  float v10 = acc10 + bx, v11 = acc11 + by;
  if (TANH) { v00 = tanhf(v00); v01 = tanhf(v01); v10 = tanhf(v10); v11 = tanhf(v11); }
  if (RES) {
    v00 += res[(size_t)m * 512 + n];       v01 += res[(size_t)m * 512 + n + 1];
    v10 += res[(size_t)(m + 1) * 512 + n]; v11 += res[(size_t)(m + 1) * 512 + n + 1];
  }
  C[(size_t)m * 512 + n] = v00;            C[(size_t)m * 512 + n + 1] = v01;
  C[(size_t)(m + 1) * 512 + n] = v10;      C[(size_t)(m + 1) * 512 + n + 1] = v11;
}

// ---------------- K4: sigmoid-gated sweep over contexts_conv ----------------
__global__ __launch_bounds__(256)
void k_sweep_conv(const float* __restrict__ ctxc, const float* __restrict__ GC,
                  float* __restrict__ CTC) {
  const int bid = blockIdx.x, tid = threadIdx.x;
  const int b = bid & 31;
  const int w = tid >> 6, lane = tid & 63;
  const float* gl = GC + (size_t)bid * H_ + lane * 8;
  const float4 g0 = *(const float4*)gl;
  const float4 g1 = *(const float4*)(gl + 4);
  float4 a0 = {0, 0, 0, 0}, a1 = {0, 0, 0, 0};
  const float* base = ctxc + (size_t)b * S_ * H_ + lane * 8;
  for (int i = 0; i < 128; ++i) {
    const int s = i * 4 + w;
    const float* xr = base + (size_t)s * H_;
    const float4 x0 = *(const float4*)(xr);
    const float4 x1 = *(const float4*)(xr + 4);
    float p = dot4(x0, g0) + dot4(x1, g1);
#pragma unroll
    for (int off = 32; off >= 1; off >>= 1) p += __shfl_xor(p, off, 64);
    const float wt = sigm(p);
    fma4(a0, wt, x0); fma4(a1, wt, x1);
  }
  __shared__ __align__(16) float part[4 * 512];
  *(float4*)&part[w * 512 + lane * 8] = a0;
  *(float4*)&part[w * 512 + lane * 8 + 4] = a1;
  __syncthreads();
  float sA = 0.f, sB = 0.f;
#pragma unroll
  for (int w8 = 0; w8 < 4; ++w8) {
    sA += part[w8 * 512 + tid];
    sB += part[w8 * 512 + 256 + tid];
  }
  CTC[(size_t)bid * H_ + tid] = sA;
  CTC[(size_t)bid * H_ + 256 + tid] = sB;
}

// ---------------- K7: online-softmax sweep over contexts ----------------
__global__ __launch_bounds__(256)
void k_sweep_att(const float* __restrict__ ctx, const float* __restrict__ GA,
                 float* __restrict__ CT) {
  const int bid = blockIdx.x, tid = threadIdx.x;
  const int b = bid & 31;
  const int w = tid >> 6, lane = tid & 63;
  const float* gl = GA + (size_t)bid * H_ + lane * 8;
  const float4 g0 = *(const float4*)gl;
  const float4 g1 = *(const float4*)(gl + 4);
  float4 a0 = {0, 0, 0, 0}, a1 = {0, 0, 0, 0};
  float m = -1e30f, l = 0.f;
  const float* base = ctx + (size_t)b * S_ * H_ + lane * 8;
  for (int i = 0; i < 128; ++i) {
    const int s = i * 4 + w;
    const float* xr = base + (size_t)s * H_;
    const float4 x0 = *(const float4*)(xr);
    const float4 x1 = *(const float4*)(xr + 4);
    float p = dot4(x0, g0) + dot4(x1, g1);
#pragma unroll
    for (int off = 32; off >= 1; off >>= 1) p += __shfl_xor(p, off, 64);
    const float m2 = fmaxf(m, p);
    const float f = expf(m - m2);
    const float e = expf(p - m2);
    l = l * f + e;
    scale_fma4(a0, f, e, x0);
    scale_fma4(a1, f, e, x1);
    m = m2;
  }
  __shared__ __align__(16) float part[4 * 512 + 8];
  *(float4*)&part[w * 512 + lane * 8] = a0;
  *(float4*)&part[w * 512 + lane * 8 + 4] = a1;
  if (lane == 0) { part[2048 + w * 2] = m; part[2048 + w * 2 + 1] = l; }
  __syncthreads();
  float M = part[2048];
#pragma unroll
  for (int w8 = 1; w8 < 4; ++w8) M = fmaxf(M, part[2048 + w8 * 2]);
  float fac[4], L = 0.f;
#pragma unroll
  for (int w8 = 0; w8 < 4; ++w8) {
    fac[w8] = expf(part[2048 + w8 * 2] - M);
    L += fac[w8] * part[2048 + w8 * 2 + 1];
  }
  const float inv = 1.0f / L;
  float sA = 0.f, sB = 0.f;
#pragma unroll
  for (int w8 = 0; w8 < 4; ++w8) {
    sA += fac[w8] * part[w8 * 512 + tid];
    sB += fac[w8] * part[w8 * 512 + 256 + tid];
  }
  CT[(size_t)bid * H_ + tid] = sA * inv;
  CT[(size_t)bid * H_ + 256 + tid] = sB * inv;
}

extern "C" void kernel_launch(void* const* d_in, const int* in_sizes, int n_in,
                              void* d_out, int out_size, void* d_ws, size_t ws_size,
                              hipStream_t stream) {
  const int*   inputs  = (const int*)d_in[0];
  const float* h0in    = (const float*)d_in[1];
  const float* c0in    = (const float*)d_in[2];
  const float* ctx     = (const float*)d_in[3];
  const float* ctxc    = (const float*)d_in[4];
  const float* emb     = (const float*)d_in[5];
  const float* W_ih    = (const float*)d_in[6];
  const float* W_hh    = (const float*)d_in[7];
  const float* b_ih    = (const float*)d_in[8];
  const float* b_hh    = (const float*)d_in[9];
  const float* Wi_att  = (const float*)d_in[10];
  const float* bi_att  = (const float*)d_in[11];
  const float* Wo_att  = (const float*)d_in[12];
  const float* bo_att  = (const float*)d_in[13];
  const float* Wi_conv = (const float*)d_in[14];
  const float* bi_conv = (const float*)d_in[15];
  const float* Wo_conv = (const float*)d_in[16];
  const float* bo_conv = (const float*)d_in[17];
  float* out = (float*)d_out;
  float* ws  = (float*)d_ws;

  float* GC  = ws + O_GC;    // gamma_conv, then gamma_att
  float* CTC = ws + O_CTC;   // ct_conv, then ct_att
  float* OCV = ws + O_OCV;   // out_conv

  k_init<<<dim3(256), dim3(512), 0, stream>>>(inputs, h0in, emb, ws);
  k_lstm<<<dim3(LSTM_NWG), dim3(512), 0, stream>>>(W_ih, W_hh, b_ih, b_hh,
                                                   c0in, out, ws);
  // gamma_conv = XH @ Wi_conv^T + bi_conv   (XH stashed in out)
  k_gemm<false, false><<<dim3(512), dim3(256), 0, stream>>>(
      out, nullptr, Wi_conv, bi_conv, nullptr, GC, 0);
  k_sweep_conv<<<dim3(1024), dim3(256), 0, stream>>>(ctxc, GC, CTC);
  // out_conv = tanh([ct_c | XH] @ Wo_conv^T + bo_conv)
  k_gemm<true, false><<<dim3(512), dim3(256), 0, stream>>>(
      CTC, out, Wo_conv, bo_conv, nullptr, OCV, 1);
  // gamma_att = OCV @ Wi_att^T + bi_att
  k_gemm<false, false><<<dim3(512), dim3(256), 0, stream>>>(
      OCV, nullptr, Wi_att, bi_att, nullptr, GC, 0);
  k_sweep_att<<<dim3(1024), dim3(256), 0, stream>>>(ctx, GC, CTC);
  // out = tanh([ct | OCV] @ Wo_att^T + bo_att) + OCV
  k_gemm<true, true><<<dim3(512), dim3(256), 0, stream>>>(
      CTC, OCV, Wo_att, bo_att, OCV, out, 1);
}

// Round 12
// 1471.628 us; speedup vs baseline: 3.1265x; 3.1265x over previous
//
#include <hip/hip_runtime.h>
#include <math.h>

namespace {
constexpr int T_ = 32, B_ = 32, H_ = 512, S_ = 512;
constexpr int BH = B_ * H_;     // 16384
constexpr int LSTM_NWG = 256;
// ws float offsets
constexpr size_t O_EMBS = 0;                          // [T*B][H]
constexpr size_t O_H0   = O_EMBS + (size_t)T_ * BH;   // [2][BH]
constexpr size_t O_H1   = O_H0 + 2 * BH;              // [2][BH]
constexpr size_t O_GC   = O_H1 + 2 * BH;              // gamma [1024][512]
constexpr size_t O_CTC  = O_GC + (size_t)1024 * 512;  // ct
constexpr size_t O_OCV  = O_CTC + (size_t)1024 * 512; // out_conv
}

// Monotonic barrier state (zero-init at load, survives graph replays, immune
// to 0xAA ws poison). Used only by k_lstm.
__device__ unsigned g_arrive[LSTM_NWG] = {};
__device__ unsigned g_go = 0;

static __device__ __forceinline__ float sigm(float x) { return 1.0f / (1.0f + expf(-x)); }
static __device__ __forceinline__ float dot4(float4 a, float4 b) {
  return a.x * b.x + a.y * b.y + a.z * b.z + a.w * b.w;
}
static __device__ __forceinline__ void fma4(float4& a, float s, float4 x) {
  a.x += s * x.x; a.y += s * x.y; a.z += s * x.z; a.w += s * x.w;
}
static __device__ __forceinline__ void scale_fma4(float4& a, float f, float e, float4 x) {
  a.x = a.x * f + e * x.x; a.y = a.y * f + e * x.y;
  a.z = a.z * f + e * x.z; a.w = a.w * f + e * x.w;
}

// Fence-free grid barrier (validated round 7). Cross-WG data moves via sc1
// accesses that bypass L2; barrier needs only vmcnt drain + flag atomics.
static __device__ __forceinline__ void grid_barrier_light(unsigned target) {
  asm volatile("s_waitcnt vmcnt(0)" ::: "memory");  // drain own sc1 h-stores
  __syncthreads();
  if (threadIdx.x == 0)
    __hip_atomic_store(&g_arrive[blockIdx.x], target, __ATOMIC_RELAXED,
                       __HIP_MEMORY_SCOPE_AGENT);
  if (blockIdx.x == 0) {
    for (int i = threadIdx.x; i < LSTM_NWG; i += 512)
      while (__hip_atomic_load(&g_arrive[i], __ATOMIC_RELAXED,
                               __HIP_MEMORY_SCOPE_AGENT) < target)
        __builtin_amdgcn_s_sleep(1);
    __syncthreads();
    if (threadIdx.x == 0)
      __hip_atomic_store(&g_go, target, __ATOMIC_RELAXED,
                         __HIP_MEMORY_SCOPE_AGENT);
  }
  if (threadIdx.x == 0)
    while (__hip_atomic_load(&g_go, __ATOMIC_RELAXED,
                             __HIP_MEMORY_SCOPE_AGENT) < target)
      __builtin_amdgcn_s_sleep(1);
  __syncthreads();
  asm volatile("" ::: "memory");   // compiler barrier: no load hoisting
}

// ---------------- K1: init state + embedding gather ----------------
__global__ __launch_bounds__(512)
void k_init(const int* __restrict__ inputs, const float* __restrict__ h0in,
            const float* __restrict__ emb, float* __restrict__ ws) {
  const int g = blockIdx.x, tid = threadIdx.x;
  const int gid = g * 512 + tid;
  // Ping parity: layer-0 initial h in ping 0; layer-1 initial h in ping 1.
  if (gid < BH) {
    ws[O_H0 + gid]      = h0in[gid];
    ws[O_H1 + BH + gid] = h0in[BH + gid];
  }
#pragma unroll
  for (int r = 0; r < 4; ++r) {
    const int tb = g * 4 + r;
    ws[O_EMBS + (size_t)tb * H_ + tid] = emb[(size_t)inputs[tb] * H_ + tid];
  }
}

// ---------------- K2: persistent LSTM chain, phase-split MAC ----------------
// 256 WGs x 512 threads, 1 WG/CU. WG = (cell = g>>7, quad q = g&127) owning
// cols j = q*4..+3. Thread = (jj = tid&3 col, gp = (tid>>2)&1 gate-pair,
// ks = (tid>>3)&31 K-window of 16, b8 = tid>>8 b-half of 16).
// Weights live in LDS permanently (wlds[16 rows][1028], row = col*4+gate,
// cols 0..511 = Wih row, 512..1023 = Whh row). Each stage: stage x -> MAC-X
// (8 weight-f4 in regs) -> stage h into SAME buffer -> MAC-H. Peak live regs
// ~= w32 + acc32 + tmp16 + addr ~ 105 << 128 cap. Rounds 9-11 lesson: any
// design whose demand exceeds the immovable 128-VGPR cap spills its big
// arrays to scratch (10-13 GB HBM traffic); sit comfortably under the cap.
__global__ __launch_bounds__(512)
void k_lstm(const float* __restrict__ W_ih, const float* __restrict__ W_hh,
            const float* __restrict__ b_ih, const float* __restrict__ b_hh,
            const float* __restrict__ c0in, float* __restrict__ out,
            float* __restrict__ ws) {
  const int g = blockIdx.x, tid = threadIdx.x;
  const int cell = g >> 7, q = g & 127;
  const int jj = tid & 3, gp = (tid >> 2) & 1, ks = (tid >> 3) & 31, b8 = tid >> 8;
  float* EMBS = ws + O_EMBS;
  float* H0 = ws + O_H0;
  float* H1 = ws + O_H1;

  __shared__ __align__(16) float wlds[16 * 1028];   // weights, persistent, 66 KB
  __shared__ __align__(16) float stg[16512];        // x / h / red, 66 KB
  __shared__ float gates[512];

  // ---- one-time: weights into LDS (persistent). Per pass: 16 rows x 512
  // floats = 2048 float4 -> i<4. lrow = col*4 + gate; pass0 = Wih half
  // (offset 0), pass1 = Whh half (offset 512).
  {
    const float* Wih = W_ih + (size_t)cell * 4 * H_ * H_;
    const float* Whh = W_hh + (size_t)cell * 4 * H_ * H_;
#pragma unroll
    for (int pass = 0; pass < 2; ++pass) {
      const float* Wsrc = pass ? Whh : Wih;
#pragma unroll
      for (int i = 0; i < 4; ++i) {
        const int d4 = tid + i * 512;          // float4 idx 0..2047
        const int lrow = d4 >> 7;              // 0..15 = col*4 + gate
        const int f4 = d4 & 127;               // 0..127
        const int rr = lrow & 3, jx = lrow >> 2;
        const float4 v = *(const float4*)&Wsrc[((size_t)rr * H_ + q * 4 + jx) * H_ + f4 * 4];
        *(float4*)&wlds[lrow * 1028 + pass * 512 + f4 * 4] = v;
      }
    }
  }
  // ---- one-time: bias sums + c-state for finalize threads (tid < 128) ----
  float creg = 0.f, bs0 = 0.f, bs1 = 0.f, bs2 = 0.f, bs3 = 0.f;
  if (tid < 128) {
    const int fj = tid >> 5, fb = tid & 31;
    const int fjo = q * 4 + fj;
    creg = c0in[cell * BH + fb * H_ + fjo];
    const float* bi = b_ih + (size_t)cell * 4 * H_;
    const float* bh = b_hh + (size_t)cell * 4 * H_;
    bs0 = bi[0 * H_ + fjo] + bh[0 * H_ + fjo];
    bs1 = bi[1 * H_ + fjo] + bh[1 * H_ + fjo];
    bs2 = bi[2 * H_ + fjo] + bh[2 * H_ + fjo];
    bs3 = bi[3 * H_ + fjo] + bh[3 * H_ + fjo];
  }
  __syncthreads();   // wlds visible to all

  const int rowA = jj * 4 + gp * 2;    // gate gp*2 of col jj
  const int rowB = rowA + 1;           // gate gp*2+1

  unsigned bar = __hip_atomic_load(&g_go, __ATOMIC_RELAXED,
                                   __HIP_MEMORY_SCOPE_AGENT);

  for (int s = 0; s <= T_; ++s) {
    const int pi = s & 1, qi = pi ^ 1;
    const bool act = cell ? (s >= 1) : (s < T_);   // WG-uniform
    if (act) {
      float acc_a[16], acc_b[16];

      // ======== phase X: stage x operand, MAC with x-half weights ========
      if (cell == 0) {   // x = EMBS[s] (normal cached loads, L2-hot)
        const float* src = EMBS + (size_t)s * BH;
#pragma unroll 4
        for (int i = 0; i < 8; ++i) {
          const int d = tid + i * 512;
          const int b = d >> 7, k4 = d & 127;
          const float4 v = *(const float4*)(src + b * 512 + k4 * 4);
          *(float4*)&stg[(k4 >> 2) * 516 + b * 16 + (k4 & 3) * 4] = v;
        }
      } else {           // x = H0[pi] (sc1 coherent)
        const float* src = H0 + pi * BH;
#pragma unroll 4
        for (int i = 0; i < 8; ++i) {
          const int d = tid + i * 512;
          const int b = d >> 7, k4 = d & 127;
          const float* p = src + b * 512 + k4 * 4;
          const unsigned long long u0 = __hip_atomic_load(
              (const unsigned long long*)p, __ATOMIC_RELAXED, __HIP_MEMORY_SCOPE_AGENT);
          const unsigned long long u1 = __hip_atomic_load(
              (const unsigned long long*)(p + 2), __ATOMIC_RELAXED, __HIP_MEMORY_SCOPE_AGENT);
          float4 v;
          v.x = __uint_as_float((unsigned)u0); v.y = __uint_as_float((unsigned)(u0 >> 32));
          v.z = __uint_as_float((unsigned)u1); v.w = __uint_as_float((unsigned)(u1 >> 32));
          *(float4*)&stg[(k4 >> 2) * 516 + b * 16 + (k4 & 3) * 4] = v;
        }
      }
      __syncthreads();
      {
        float4 wa0, wa1, wa2, wa3, wb0, wb1, wb2, wb3;
        wa0 = *(const float4*)&wlds[rowA * 1028 + ks * 16 + 0];
        wa1 = *(const float4*)&wlds[rowA * 1028 + ks * 16 + 4];
        wa2 = *(const float4*)&wlds[rowA * 1028 + ks * 16 + 8];
        wa3 = *(const float4*)&wlds[rowA * 1028 + ks * 16 + 12];
        wb0 = *(const float4*)&wlds[rowB * 1028 + ks * 16 + 0];
        wb1 = *(const float4*)&wlds[rowB * 1028 + ks * 16 + 4];
        wb2 = *(const float4*)&wlds[rowB * 1028 + ks * 16 + 8];
        wb3 = *(const float4*)&wlds[rowB * 1028 + ks * 16 + 12];
#pragma unroll
        for (int bi = 0; bi < 16; ++bi) {
          const float* hp = &stg[ks * 516 + (b8 * 16 + bi) * 16];
          const float4 h0 = *(const float4*)(hp);
          const float4 h1 = *(const float4*)(hp + 4);
          const float4 h2 = *(const float4*)(hp + 8);
          const float4 h3 = *(const float4*)(hp + 12);
          acc_a[bi] = dot4(h0, wa0) + dot4(h1, wa1) + dot4(h2, wa2) + dot4(h3, wa3);
          acc_b[bi] = dot4(h0, wb0) + dot4(h1, wb1) + dot4(h2, wb2) + dot4(h3, wb3);
        }
      }
      __syncthreads();   // stg consumed; restage with h

      // ======== phase H: stage h operand, MAC with h-half weights ========
      {
        const float* src = (cell ? H1 : H0) + pi * BH;
#pragma unroll 4
        for (int i = 0; i < 8; ++i) {
          const int d = tid + i * 512;
          const int b = d >> 7, k4 = d & 127;
          const float* p = src + b * 512 + k4 * 4;
          const unsigned long long u0 = __hip_atomic_load(
              (const unsigned long long*)p, __ATOMIC_RELAXED, __HIP_MEMORY_SCOPE_AGENT);
          const unsigned long long u1 = __hip_atomic_load(
              (const unsigned long long*)(p + 2), __ATOMIC_RELAXED, __HIP_MEMORY_SCOPE_AGENT);
          float4 v;
          v.x = __uint_as_float((unsigned)u0); v.y = __uint_as_float((unsigned)(u0 >> 32));
          v.z = __uint_as_float((unsigned)u1); v.w = __uint_as_float((unsigned)(u1 >> 32));
          *(float4*)&stg[(k4 >> 2) * 516 + b * 16 + (k4 & 3) * 4] = v;
        }
      }
      __syncthreads();
      {
        float4 wa0, wa1, wa2, wa3, wb0, wb1, wb2, wb3;
        wa0 = *(const float4*)&wlds[rowA * 1028 + 512 + ks * 16 + 0];
        wa1 = *(const float4*)&wlds[rowA * 1028 + 512 + ks * 16 + 4];
        wa2 = *(const float4*)&wlds[rowA * 1028 + 512 + ks * 16 + 8];
        wa3 = *(const float4*)&wlds[rowA * 1028 + 512 + ks * 16 + 12];
        wb0 = *(const float4*)&wlds[rowB * 1028 + 512 + ks * 16 + 0];
        wb1 = *(const float4*)&wlds[rowB * 1028 + 512 + ks * 16 + 4];
        wb2 = *(const float4*)&wlds[rowB * 1028 + 512 + ks * 16 + 8];
        wb3 = *(const float4*)&wlds[rowB * 1028 + 512 + ks * 16 + 12];
#pragma unroll
        for (int bi = 0; bi < 16; ++bi) {
          const float* hp = &stg[ks * 516 + (b8 * 16 + bi) * 16];
          const float4 h0 = *(const float4*)(hp);
          const float4 h1 = *(const float4*)(hp + 4);
          const float4 h2 = *(const float4*)(hp + 8);
          const float4 h3 = *(const float4*)(hp + 12);
          acc_a[bi] += dot4(h0, wa0) + dot4(h1, wa1) + dot4(h2, wa2) + dot4(h3, wa3);
          acc_b[bi] += dot4(h0, wb0) + dot4(h1, wb1) + dot4(h2, wb2) + dot4(h3, wb3);
        }
      }
      __syncthreads();   // stg consumed; stg becomes red

      // ---- K-reduction: red[ks][row:16][b:32], stride 516 ----
      float* red = stg;
#pragma unroll
      for (int c = 0; c < 4; ++c) {
        *(float4*)&red[ks * 516 + rowA * 32 + b8 * 16 + c * 4] =
            make_float4(acc_a[c * 4], acc_a[c * 4 + 1],
                        acc_a[c * 4 + 2], acc_a[c * 4 + 3]);
        *(float4*)&red[ks * 516 + rowB * 32 + b8 * 16 + c * 4] =
            make_float4(acc_b[c * 4], acc_b[c * 4 + 1],
                        acc_b[c * 4 + 2], acc_b[c * 4 + 3]);
      }
      __syncthreads();
      {
        const int row = tid >> 5, bb = tid & 31;
        float sum = 0.f;
#pragma unroll
        for (int k2 = 0; k2 < 32; ++k2) sum += red[k2 * 516 + row * 32 + bb];
        gates[row * 32 + bb] = sum;
      }
      __syncthreads();

      // ---- finalize: 128 threads = (fj in 4 cols, fb in 32 b) ----
      if (tid < 128) {
        const int fj = tid >> 5, fb = tid & 31;
        const int fjo = q * 4 + fj;
        const float gi  = gates[(fj * 4 + 0) * 32 + fb] + bs0;
        const float gf  = gates[(fj * 4 + 1) * 32 + fb] + bs1;
        const float gg  = gates[(fj * 4 + 2) * 32 + fb] + bs2;
        const float go_ = gates[(fj * 4 + 3) * 32 + fb] + bs3;
        const float cn = sigm(gf) * creg + sigm(gi) * tanhf(gg);
        const float hn = sigm(go_) * tanhf(cn);
        creg = cn;
        float* Hs = cell ? H1 : H0;
        __hip_atomic_store(&Hs[qi * BH + fb * H_ + fjo], hn,
                           __ATOMIC_RELAXED, __HIP_MEMORY_SCOPE_AGENT);
        if (cell)  // stash h1(t) rows (XH) in out[t]
          out[((size_t)(s - 1) * B_ + fb) * H_ + fjo] = hn;
        if (!cell && s == T_ - 1) {   // final h0/c0
          out[(size_t)T_ * BH + fb * H_ + fjo]          = hn;
          out[(size_t)T_ * BH + 2 * BH + fb * H_ + fjo] = cn;
        }
        if (cell && s == T_) {        // final h1/c1
          out[(size_t)T_ * BH + BH + fb * H_ + fjo]     = hn;
          out[(size_t)T_ * BH + 3 * BH + fb * H_ + fjo] = cn;
        }
      }
    }
    if (s < T_) grid_barrier_light(++bar);
  }
}

// ---------------- tiled GEMM: C[m][n] = ep(A[m][:] . W[n][:] + bias[n]) ----
template<bool TANH, bool RES>
__global__ __launch_bounds__(256)
void k_gemm(const float* __restrict__ A1, const float* __restrict__ A2,
            const float* __restrict__ W, const float* __restrict__ bias,
            const float* __restrict__ res, float* __restrict__ C, int dualA) {
  const int bid = blockIdx.x, tid = threadIdx.x;
  const int m0 = (bid & 31) * 32, n0 = (bid >> 5) * 32;
  const int tx = tid & 15, ty = tid >> 4;
  const int lr = tid >> 5, lc = tid & 31;
  const int nsteps = dualA ? 32 : 16;
  const int Krow = dualA ? 1024 : 512;
  __shared__ __align__(16) float Asm[32 * 33];
  __shared__ __align__(16) float Bsm[32 * 34];
  float acc00 = 0.f, acc01 = 0.f, acc10 = 0.f, acc11 = 0.f;

  for (int kt = 0; kt < nsteps; ++kt) {
    const float* A = (kt < 16) ? A1 : A2;
    const int ka = (kt < 16) ? kt * 32 : (kt - 16) * 32;
    const int kb = kt * 32;
    __syncthreads();
#pragma unroll
    for (int i = 0; i < 4; ++i) {
      const int row = lr + i * 8;
      Asm[row * 33 + lc] = A[(size_t)(m0 + row) * 512 + ka + lc];
      Bsm[lc * 34 + row] = W[(size_t)(n0 + row) * Krow + kb + lc];
    }
    __syncthreads();
#pragma unroll 8
    for (int k = 0; k < 32; ++k) {
      const float a0 = Asm[(ty * 2) * 33 + k];
      const float a1 = Asm[(ty * 2 + 1) * 33 + k];
      const float2 bv = *(const float2*)&Bsm[k * 34 + tx * 2];
      acc00 += a0 * bv.x; acc01 += a0 * bv.y;
      acc10 += a1 * bv.x; acc11 += a1 * bv.y;
    }
  }
  const int n = n0 + tx * 2;
  const int m = m0 + ty * 2;
  const float bx = bias[n], by = bias[n + 1];
  float v00 = acc00 + bx, v01 = acc01 + by;
  float v10 = acc10 + bx, v11 = acc11 + by;
  if (TANH) { v00 = tanhf(v00); v01 = tanhf(v01); v10 = tanhf(v10); v11 = tanhf(v11); }
  if (RES) {
    v00 += res[(size_t)m * 512 + n];       v01 += res[(size_t)m * 512 + n + 1];
    v10 += res[(size_t)(m + 1) * 512 + n]; v11 += res[(size_t)(m + 1) * 512 + n + 1];
  }
  C[(size_t)m * 512 + n] = v00;            C[(size_t)m * 512 + n + 1] = v01;
  C[(size_t)(m + 1) * 512 + n] = v10;      C[(size_t)(m + 1) * 512 + n + 1] = v11;
}

// ---------------- K4: sigmoid-gated sweep over contexts_conv ----------------
__global__ __launch_bounds__(256)
void k_sweep_conv(const float* __restrict__ ctxc, const float* __restrict__ GC,
                  float* __restrict__ CTC) {
  const int bid = blockIdx.x, tid = threadIdx.x;
  const int b = bid & 31;
  const int w = tid >> 6, lane = tid & 63;
  const float* gl = GC + (size_t)bid * H_ + lane * 8;
  const float4 g0 = *(const float4*)gl;
  const float4 g1 = *(const float4*)(gl + 4);
  float4 a0 = {0, 0, 0, 0}, a1 = {0, 0, 0, 0};
  const float* base = ctxc + (size_t)b * S_ * H_ + lane * 8;
  for (int i = 0; i < 128; ++i) {
    const int s = i * 4 + w;
    const float* xr = base + (size_t)s * H_;
    const float4 x0 = *(const float4*)(xr);
    const float4 x1 = *(const float4*)(xr + 4);
    float p = dot4(x0, g0) + dot4(x1, g1);
#pragma unroll
    for (int off = 32; off >= 1; off >>= 1) p += __shfl_xor(p, off, 64);
    const float wt = sigm(p);
    fma4(a0, wt, x0); fma4(a1, wt, x1);
  }
  __shared__ __align__(16) float part[4 * 512];
  *(float4*)&part[w * 512 + lane * 8] = a0;
  *(float4*)&part[w * 512 + lane * 8 + 4] = a1;
  __syncthreads();
  float sA = 0.f, sB = 0.f;
#pragma unroll
  for (int w8 = 0; w8 < 4; ++w8) {
    sA += part[w8 * 512 + tid];
    sB += part[w8 * 512 + 256 + tid];
  }
  CTC[(size_t)bid * H_ + tid] = sA;
  CTC[(size_t)bid * H_ + 256 + tid] = sB;
}

// ---------------- K7: online-softmax sweep over contexts ----------------
__global__ __launch_bounds__(256)
void k_sweep_att(const float* __restrict__ ctx, const float* __restrict__ GA,
                 float* __restrict__ CT) {
  const int bid = blockIdx.x, tid = threadIdx.x;
  const int b = bid & 31;
  const int w = tid >> 6, lane = tid & 63;
  const float* gl = GA + (size_t)bid * H_ + lane * 8;
  const float4 g0 = *(const float4*)gl;
  const float4 g1 = *(const float4*)(gl + 4);
  float4 a0 = {0, 0, 0, 0}, a1 = {0, 0, 0, 0};
  float m = -1e30f, l = 0.f;
  const float* base = ctx + (size_t)b * S_ * H_ + lane * 8;
  for (int i = 0; i < 128; ++i) {
    const int s = i * 4 + w;
    const float* xr = base + (size_t)s * H_;
    const float4 x0 = *(const float4*)(xr);
    const float4 x1 = *(const float4*)(xr + 4);
    float p = dot4(x0, g0) + dot4(x1, g1);
#pragma unroll
    for (int off = 32; off >= 1; off >>= 1) p += __shfl_xor(p, off, 64);
    const float m2 = fmaxf(m, p);
    const float f = expf(m - m2);
    const float e = expf(p - m2);
    l = l * f + e;
    scale_fma4(a0, f, e, x0);
    scale_fma4(a1, f, e, x1);
    m = m2;
  }
  __shared__ __align__(16) float part[4 * 512 + 8];
  *(float4*)&part[w * 512 + lane * 8] = a0;
  *(float4*)&part[w * 512 + lane * 8 + 4] = a1;
  if (lane == 0) { part[2048 + w * 2] = m; part[2048 + w * 2 + 1] = l; }
  __syncthreads();
  float M = part[2048];
#pragma unroll
  for (int w8 = 1; w8 < 4; ++w8) M = fmaxf(M, part[2048 + w8 * 2]);
  float fac[4], L = 0.f;
#pragma unroll
  for (int w8 = 0; w8 < 4; ++w8) {
    fac[w8] = expf(part[2048 + w8 * 2] - M);
    L += fac[w8] * part[2048 + w8 * 2 + 1];
  }
  const float inv = 1.0f / L;
  float sA = 0.f, sB = 0.f;
#pragma unroll
  for (int w8 = 0; w8 < 4; ++w8) {
    sA += fac[w8] * part[w8 * 512 + tid];
    sB += fac[w8] * part[w8 * 512 + 256 + tid];
  }
  CT[(size_t)bid * H_ + tid] = sA * inv;
  CT[(size_t)bid * H_ + 256 + tid] = sB * inv;
}

extern "C" void kernel_launch(void* const* d_in, const int* in_sizes, int n_in,
                              void* d_out, int out_size, void* d_ws, size_t ws_size,
                              hipStream_t stream) {
  const int*   inputs  = (const int*)d_in[0];
  const float* h0in    = (const float*)d_in[1];
  const float* c0in    = (const float*)d_in[2];
  const float* ctx     = (const float*)d_in[3];
  const float* ctxc    = (const float*)d_in[4];
  const float* emb     = (const float*)d_in[5];
  const float* W_ih    = (const float*)d_in[6];
  const float* W_hh    = (const float*)d_in[7];
  const float* b_ih    = (const float*)d_in[8];
  const float* b_hh    = (const float*)d_in[9];
  const float* Wi_att  = (const float*)d_in[10];
  const float* bi_att  = (const float*)d_in[11];
  const float* Wo_att  = (const float*)d_in[12];
  const float* bo_att  = (const float*)d_in[13];
  const float* Wi_conv = (const float*)d_in[14];
  const float* bi_conv = (const float*)d_in[15];
  const float* Wo_conv = (const float*)d_in[16];
  const float* bo_conv = (const float*)d_in[17];
  float* out = (float*)d_out;
  float* ws  = (float*)d_ws;

  float* GC  = ws + O_GC;    // gamma_conv, then gamma_att
  float* CTC = ws + O_CTC;   // ct_conv, then ct_att
  float* OCV = ws + O_OCV;   // out_conv

  k_init<<<dim3(256), dim3(512), 0, stream>>>(inputs, h0in, emb, ws);
  k_lstm<<<dim3(LSTM_NWG), dim3(512), 0, stream>>>(W_ih, W_hh, b_ih, b_hh,
                                                   c0in, out, ws);
  // gamma_conv = XH @ Wi_conv^T + bi_conv   (XH stashed in out)
  k_gemm<false, false><<<dim3(512), dim3(256), 0, stream>>>(
      out, nullptr, Wi_conv, bi_conv, nullptr, GC, 0);
  k_sweep_conv<<<dim3(1024), dim3(256), 0, stream>>>(ctxc, GC, CTC);
  // out_conv = tanh([ct_c | XH] @ Wo_conv^T + bo_conv)
  k_gemm<true, false><<<dim3(512), dim3(256), 0, stream>>>(
      CTC, out, Wo_conv, bo_conv, nullptr, OCV, 1);
  // gamma_att = OCV @ Wi_att^T + bi_att
  k_gemm<false, false><<<dim3(512), dim3(256), 0, stream>>>(
      OCV, nullptr, Wi_att, bi_att, nullptr, GC, 0);
  k_sweep_att<<<dim3(1024), dim3(256), 0, stream>>>(ctx, GC, CTC);
  // out = tanh([ct | OCV] @ Wo_att^T + bo_att) + OCV
  k_gemm<true, true><<<dim3(512), dim3(256), 0, stream>>>(
      CTC, OCV, Wo_att, bo_att, OCV, out, 1);
}